// Round 18
// baseline (32.788 us; speedup 1.0000x reference)
//
#include <hip/hip_runtime.h>

#define KN    4096
#define LTOT  6
#define BATCH 8192
#define NBLK  64
#define NTH   64                 // 1 wave per block, 64 blocks <= 256 CUs (co-resident)

#if __has_builtin(__builtin_amdgcn_cvt_pk_u8_f32)
#define CVT_PK_U8(o, r, enc) __builtin_amdgcn_cvt_pk_u8_f32((o), (r), (enc))
#else
#define CVT_PK_U8(o, r, enc) ((enc) | ((unsigned)(int)(o) << (8 * (r))))
#endif

// Reconstruct scaled float coefficients (+0.5 rounding bias folded) from u8 corners.
#define COEFFS(CW)                                                              \
    float W00 = (float)((CW) & 0xffu);                                          \
    float W01 = (float)(((CW) >> 8) & 0xffu);                                   \
    float W10 = (float)(((CW) >> 16) & 0xffu);                                  \
    float W11 = (float)((CW) >> 24);                                            \
    float C1  = W00 + 0.5f;                                                     \
    float CA  = (W10 - W00) * (1.f / 255.f);                                    \
    float CB  = (W01 - W00) * (1.f / 255.f);                                    \
    float CAB = (W11 - W10 - W01 + W00) * (1.f / 65025.f);

// Device-scope spin barrier over NBLK blocks. Monotonic counter; target = NBLK*phase.
// Correct regardless of block->XCD mapping (agent-scope atomics). All cross-block
// payloads (tables, gsum) are agent-scope atomics, sequenced by this acq_rel pair.
__device__ __forceinline__ void gbar(unsigned* ctr, unsigned target) {
    __syncthreads();
    if (threadIdx.x == 0) {
        __hip_atomic_fetch_add(ctr, 1u, __ATOMIC_ACQ_REL, __HIP_MEMORY_SCOPE_AGENT);
        while (__hip_atomic_load(ctr, __ATOMIC_ACQUIRE, __HIP_MEMORY_SCOPE_AGENT) < target) {}
    }
    __syncthreads();
}

// ONE kernel: thread t owns neuron (blockIdx*64+t) of EVERY layer. Weights and
// indices for all 6 layers live in this thread's registers (no operand round-trip).
// Only the 16 KB u8x4-per-pattern activation tables cross blocks, via global
// memory + spin barrier. Layer-5 class sums: integer atomics (deterministic).
__global__ __launch_bounds__(NTH) void fused_all(const float* __restrict__ x,
                                                 const float* __restrict__ w0,
                                                 const float* __restrict__ ws,
                                                 const int* __restrict__ idx0,
                                                 const int* __restrict__ idxs,
                                                 unsigned* __restrict__ ctr,
                                                 unsigned* __restrict__ gsum,
                                                 unsigned* __restrict__ tbl,
                                                 float2* __restrict__ out) {
    const float TABC[16][4] = {
        {0.f, 0.f, 0.f, 0.f}, {0.f, 0.f, 0.f, 1.f}, {0.f, 1.f, 0.f,-1.f}, {0.f, 1.f, 0.f, 0.f},
        {0.f, 0.f, 1.f,-1.f}, {0.f, 0.f, 1.f, 0.f}, {0.f, 1.f, 1.f,-2.f}, {0.f, 1.f, 1.f,-1.f},
        {1.f,-1.f,-1.f, 1.f}, {1.f,-1.f,-1.f, 2.f}, {1.f, 0.f,-1.f, 0.f}, {1.f, 0.f,-1.f, 1.f},
        {1.f,-1.f, 0.f, 0.f}, {1.f,-1.f, 0.f, 1.f}, {1.f, 0.f, 0.f,-1.f}, {1.f, 0.f, 0.f, 0.f}
    };
    const int tid = threadIdx.x;
    const int gk  = blockIdx.x * NTH + tid;     // this thread's neuron (all layers)

    // ---- Load all weights (6 x 64 B, coalesced) + all indices into registers ----
    float4 wq[LTOT][4];
#pragma unroll
    for (int l = 0; l < LTOT; ++l) {
        const float4* src = (l == 0) ? (const float4*)(w0 + (size_t)gk * 16)
                                     : (const float4*)(ws + ((size_t)(l - 1) * KN + gk) * 16);
#pragma unroll
        for (int j = 0; j < 4; ++j) wq[l][j] = src[j];
    }
    int ia[LTOT], ib[LTOT];
    ia[0] = idx0[gk];
    ib[0] = idx0[KN + gk];
#pragma unroll
    for (int l = 1; l < LTOT; ++l) {
        ia[l] = idxs[(size_t)(l - 1) * 2 * KN + gk];
        ib[l] = idxs[(size_t)(l - 1) * 2 * KN + KN + gk];
    }

    // ---- Softmax -> u8 corner pack, per layer ----
    unsigned corn[LTOT];
#pragma unroll
    for (int l = 0; l < LTOT; ++l) {
        float wv[16];
        wv[0]=wq[l][0].x; wv[1]=wq[l][0].y; wv[2]=wq[l][0].z; wv[3]=wq[l][0].w;
        wv[4]=wq[l][1].x; wv[5]=wq[l][1].y; wv[6]=wq[l][1].z; wv[7]=wq[l][1].w;
        wv[8]=wq[l][2].x; wv[9]=wq[l][2].y; wv[10]=wq[l][2].z; wv[11]=wq[l][2].w;
        wv[12]=wq[l][3].x; wv[13]=wq[l][3].y; wv[14]=wq[l][3].z; wv[15]=wq[l][3].w;
        float m = -1e30f;
#pragma unroll
        for (int j = 0; j < 16; ++j) m = fmaxf(m, wv[j]);
        float s = 0.f;
#pragma unroll
        for (int j = 0; j < 16; ++j) { wv[j] = __expf(wv[j] - m); s += wv[j]; }
        float inv = 1.0f / s;
        float c0 = 0.f, c1 = 0.f, c2 = 0.f, c3 = 0.f;
#pragma unroll
        for (int j = 0; j < 16; ++j) {
            c0 += wv[j] * TABC[j][0];
            c1 += wv[j] * TABC[j][1];
            c2 += wv[j] * TABC[j][2];
            c3 += wv[j] * TABC[j][3];
        }
        c0 *= inv; c1 *= inv; c2 *= inv; c3 *= inv;
        float w00 = c0, w01 = c0 + c2, w10 = c0 + c1, w11 = c0 + c1 + c2 + c3;
        unsigned q00 = (unsigned)min(255, max(0, (int)(w00 * 255.f + 0.5f)));
        unsigned q01 = (unsigned)min(255, max(0, (int)(w01 * 255.f + 0.5f)));
        unsigned q10 = (unsigned)min(255, max(0, (int)(w10 * 255.f + 0.5f)));
        unsigned q11 = (unsigned)min(255, max(0, (int)(w11 * 255.f + 0.5f)));
        corn[l] = q00 | (q01 << 8) | (q10 << 16) | (q11 << 24);
    }

    // ---- Layer 0: corner select per pattern (features ARE the pattern bits) ----
    {
        unsigned cw = corn[0];
        unsigned q00 = cw & 255u, q01 = (cw >> 8) & 255u, q10 = (cw >> 16) & 255u, q11 = cw >> 24;
        unsigned enc = 0;
#pragma unroll
        for (int p = 0; p < 4; ++p) {
            unsigned a = (unsigned)(ia[0] ? (p >> 1) : p) & 1u;
            unsigned b = (unsigned)(ib[0] ? (p >> 1) : p) & 1u;
            unsigned q = a ? (b ? q11 : q10) : (b ? q01 : q00);
            enc |= q << (8 * p);
        }
        __hip_atomic_store(&tbl[gk], enc, __ATOMIC_RELAXED, __HIP_MEMORY_SCOPE_AGENT);
    }
    gbar(ctr, NBLK * 1);

    // ---- Layers 1..4: gather prev table (agent-coherent), quantize, store ----
#pragma unroll
    for (int l = 1; l <= 4; ++l) {
        unsigned av = __hip_atomic_load(&tbl[(size_t)(l - 1) * KN + ia[l]],
                                        __ATOMIC_RELAXED, __HIP_MEMORY_SCOPE_AGENT);
        unsigned bv = __hip_atomic_load(&tbl[(size_t)(l - 1) * KN + ib[l]],
                                        __ATOMIC_RELAXED, __HIP_MEMORY_SCOPE_AGENT);
        COEFFS(corn[l]);
        unsigned enc = 0;
#pragma unroll
        for (int r = 0; r < 4; ++r) {
            float af = (float)((av >> (8 * r)) & 0xffu);
            float bf = (float)((bv >> (8 * r)) & 0xffu);
            float o = fmaf(fmaf(CAB, bf, CA), af, fmaf(CB, bf, C1));
            enc = CVT_PK_U8(o, r, enc);
        }
        __hip_atomic_store(&tbl[(size_t)l * KN + gk], enc,
                           __ATOMIC_RELAXED, __HIP_MEMORY_SCOPE_AGENT);
        gbar(ctr, NBLK * (l + 1));
    }

    // ---- Layer 5 + integer GroupSum (65280-scale -> deterministic u32 atomics) ----
    {
        unsigned av = __hip_atomic_load(&tbl[(size_t)4 * KN + ia[5]],
                                        __ATOMIC_RELAXED, __HIP_MEMORY_SCOPE_AGENT);
        unsigned bv = __hip_atomic_load(&tbl[(size_t)4 * KN + ib[5]],
                                        __ATOMIC_RELAXED, __HIP_MEMORY_SCOPE_AGENT);
        COEFFS(corn[5]);
        unsigned qs[4];
#pragma unroll
        for (int r = 0; r < 4; ++r) {
            float af = (float)((av >> (8 * r)) & 0xffu);
            float bf = (float)((bv >> (8 * r)) & 0xffu);
            float o = fmaf(fmaf(CAB, bf, CA), af, fmaf(CB, bf, C1));  // 255*f + 0.5
            qs[r] = (unsigned)(o * 256.0f);                           // 65280*f + 128
        }
#pragma unroll
        for (int r = 0; r < 4; ++r)
#pragma unroll
            for (int off = 32; off > 0; off >>= 1)
                qs[r] += __shfl_down(qs[r], off);
        const int cls = (gk >= KN / 2) ? 1 : 0;     // uniform per block
        if (tid == 0) {
#pragma unroll
            for (int r = 0; r < 4; ++r)
                atomicAdd(&gsum[r * 2 + cls], qs[r]);
        }
    }

    // Prefetch this block's scatter rows (independent of the final barrier).
    const float2* __restrict__ x2 = (const float2*)x;
    float2 xr0 = x2[blockIdx.x * 128 + tid];
    float2 xr1 = x2[blockIdx.x * 128 + 64 + tid];

    gbar(ctr, NBLK * 6);

    // ---- Scatter: 128 rows per block ----
    unsigned gs[8];
#pragma unroll
    for (int j = 0; j < 8; ++j)
        gs[j] = __hip_atomic_load(&gsum[j], __ATOMIC_RELAXED, __HIP_MEMORY_SCOPE_AGENT);
    const float sc = 1.0f / 65280.0f;
    {
        int p0 = (xr0.x > 0.f ? 1 : 0) | (xr0.y > 0.f ? 2 : 0);
        out[blockIdx.x * 128 + tid] =
            make_float2(((float)gs[p0 * 2 + 0] - 262144.f) * sc,
                        ((float)gs[p0 * 2 + 1] - 262144.f) * sc);
        int p1 = (xr1.x > 0.f ? 1 : 0) | (xr1.y > 0.f ? 2 : 0);
        out[blockIdx.x * 128 + 64 + tid] =
            make_float2(((float)gs[p1 * 2 + 0] - 262144.f) * sc,
                        ((float)gs[p1 * 2 + 1] - 262144.f) * sc);
    }
}

extern "C" void kernel_launch(void* const* d_in, const int* in_sizes, int n_in,
                              void* d_out, int out_size, void* d_ws, size_t ws_size,
                              hipStream_t stream) {
    const float* x    = (const float*)d_in[0];
    const float* w0   = (const float*)d_in[1];
    const float* ws   = (const float*)d_in[2];
    const int*   idx0 = (const int*)d_in[3];
    const int*   idxs = (const int*)d_in[4];
    float*       out  = (float*)d_out;

    unsigned* ctr  = (unsigned*)d_ws;          // [0]      barrier counter
    unsigned* gsum = ctr + 4;                  // [16..47] 8 class sums
    unsigned* tbl  = ctr + 16;                 // [64...]  6 x 16 KB activation tables

    hipMemsetAsync(d_ws, 0, 64, stream);       // zero ctr + gsum (in-graph, per call)
    fused_all<<<NBLK, NTH, 0, stream>>>(x, w0, ws, idx0, idxs, ctr, gsum, tbl,
                                        (float2*)out);
}

// Round 19
// 18.873 us; speedup vs baseline: 1.7373x; 1.7373x over previous
//
#include <hip/hip_runtime.h>

#define KN    4096
#define LTOT  6
#define BATCH 8192
#define NT    1024
#define NITER (KN / NT)          // 4
#define NPAT  4
#define RPT   (BATCH / NT)       // 8 rows/thread in scatter phase

// Packed operand record, 8 B/neuron (one dwordx2 into VGPRs):
//   x = (ia*4) | ((ib*4) << 16)   -- byte offsets into f32 activation LDS
//   y = u8 corners: w00 | w01<<8 | w10<<16 | w11<<24,  wRC = round(255*f(R,C))
// f is multilinear in (a,b), so the 4 corners determine it exactly; every
// corner is a convex combination of {0,1} values -> in [0,1].
__global__ __launch_bounds__(256) void pack_kernel(const float* __restrict__ w0,
                                                   const float* __restrict__ ws,
                                                   const int* __restrict__ idx0,
                                                   const int* __restrict__ idxs,
                                                   uint2* __restrict__ pk) {
    const float TAB[16][4] = {
        {0.f, 0.f, 0.f, 0.f}, {0.f, 0.f, 0.f, 1.f}, {0.f, 1.f, 0.f,-1.f}, {0.f, 1.f, 0.f, 0.f},
        {0.f, 0.f, 1.f,-1.f}, {0.f, 0.f, 1.f, 0.f}, {0.f, 1.f, 1.f,-2.f}, {0.f, 1.f, 1.f,-1.f},
        {1.f,-1.f,-1.f, 1.f}, {1.f,-1.f,-1.f, 2.f}, {1.f, 0.f,-1.f, 0.f}, {1.f, 0.f,-1.f, 1.f},
        {1.f,-1.f, 0.f, 0.f}, {1.f,-1.f, 0.f, 1.f}, {1.f, 0.f, 0.f,-1.f}, {1.f, 0.f, 0.f, 0.f}
    };
    int gid = blockIdx.x * 256 + threadIdx.x;
    if (gid >= LTOT * KN) return;
    int l = gid >> 12;
    int k = gid & (KN - 1);
    const float* w = (l == 0) ? (w0 + k * 16) : (ws + ((size_t)((l - 1) * KN + k) << 4));
    float wv[16];
    float m = -1e30f;
#pragma unroll
    for (int j = 0; j < 16; ++j) { wv[j] = w[j]; m = fmaxf(m, wv[j]); }
    float s = 0.f;
#pragma unroll
    for (int j = 0; j < 16; ++j) { wv[j] = __expf(wv[j] - m); s += wv[j]; }
    float inv = 1.0f / s;
    float c0 = 0.f, c1 = 0.f, c2 = 0.f, c3 = 0.f;
#pragma unroll
    for (int j = 0; j < 16; ++j) {
        c0 += wv[j] * TAB[j][0];
        c1 += wv[j] * TAB[j][1];
        c2 += wv[j] * TAB[j][2];
        c3 += wv[j] * TAB[j][3];
    }
    c0 *= inv; c1 *= inv; c2 *= inv; c3 *= inv;

    float w00 = c0;                    // f(0,0)
    float w01 = c0 + c2;               // f(0,1)
    float w10 = c0 + c1;               // f(1,0)
    float w11 = c0 + c1 + c2 + c3;     // f(1,1)
    unsigned q00 = (unsigned)min(255, max(0, (int)(w00 * 255.f + 0.5f)));
    unsigned q01 = (unsigned)min(255, max(0, (int)(w01 * 255.f + 0.5f)));
    unsigned q10 = (unsigned)min(255, max(0, (int)(w10 * 255.f + 0.5f)));
    unsigned q11 = (unsigned)min(255, max(0, (int)(w11 * 255.f + 0.5f)));

    int ia, ib;
    if (l == 0) { ia = idx0[k];                            ib = idx0[KN + k]; }
    else        { ia = idxs[(size_t)(l - 1) * 2 * KN + k]; ib = idxs[(size_t)(l - 1) * 2 * KN + KN + k]; }

    uint2 e;
    e.x = ((unsigned)ia * 4u) | (((unsigned)ib * 4u) << 16);
    e.y = q00 | (q01 << 8) | (q10 << 16) | (q11 << 24);
    pk[gid] = e;
}

// Reconstruct 255-scale coefficients from corners. Activations a,b and output
// o are all on the [0,255] float scale (no rounding bias, no requantization):
//   o = W00 + (W10-W00)/255*a + (W01-W00)/255*b + (W11-W10-W01+W00)/65025*a*b
#define COEFFS(CW)                                                              \
    float W00 = (float)((CW) & 0xffu);                                          \
    float W01 = (float)(((CW) >> 8) & 0xffu);                                   \
    float W10 = (float)(((CW) >> 16) & 0xffu);                                  \
    float W11 = (float)((CW) >> 24);                                            \
    float C1  = W00;                                                            \
    float CA  = (W10 - W00) * (1.f / 255.f);                                    \
    float CB  = (W01 - W00) * (1.f / 255.f);                                    \
    float CAB = (W11 - W10 - W01 + W00) * (1.f / 65025.f);

// One block per input pattern p in {0..3}. All 24 8-byte operand records per
// thread are loaded into registers up front (one overlapped burst, pinned by
// keep-alive asm). Layer loop: 2 LDS gathers + ~14 VALU + 1 LDS write per
// neuron. Activations: f32 at 255-scale in LDS ping-pong.
__global__ __launch_bounds__(NT, 4) void netscatter_kernel(const float* __restrict__ x,
                                                           const uint2* __restrict__ pk,
                                                           float2* __restrict__ out) {
    __shared__ float hbuf[2][KN];        // 32 KB activation ping-pong
    __shared__ float red[NT / 64][2];

    const int t = threadIdx.x;
    const int p = blockIdx.x;

    // ---- Operand burst: 24 dwordx2 loads, all issued before any use ----
    uint2 op[LTOT][NITER];
#pragma unroll
    for (int l = 0; l < LTOT; ++l)
#pragma unroll
        for (int i = 0; i < NITER; ++i)
            op[l][i] = pk[(size_t)l * KN + i * NT + t];

    // Scatter-phase x rows (tail work, issued in the same burst).
    const float2* __restrict__ x2 = (const float2*)x;
    float2 xr[RPT];
#pragma unroll
    for (int i = 0; i < RPT; ++i) xr[i] = x2[t + i * NT];

    // Keep-alive: force all operand loads materialized HERE (anti-sink).
#pragma unroll
    for (int l = 0; l < LTOT; ++l)
#pragma unroll
        for (int i = 0; i < NITER; ++i)
            asm volatile("" :: "v"(op[l][i].x), "v"(op[l][i].y));

    // ---- Layer 0: features are the pattern bits; output = corner select ----
#pragma unroll
    for (int i = 0; i < NITER; ++i) {
        int k = t + i * NT;
        unsigned px = op[0][i].x;
        unsigned cw = op[0][i].y;
        unsigned a = (unsigned)((px & 0xffffu) ? (p >> 1) : p) & 1u;
        unsigned b = (unsigned)((px >> 16)     ? (p >> 1) : p) & 1u;
        unsigned sh = (a * 2u + b) * 8u;       // 00->q00, 01->q01, 10->q10, 11->q11
        hbuf[0][k] = (float)((cw >> sh) & 0xffu);
    }
    __syncthreads();

    // ---- Layers 1..4: K -> K, ping-pong, operands from registers ----
#pragma unroll
    for (int l = 1; l <= 4; ++l) {
        const char* hs = (const char*)&hbuf[(l + 1) & 1][0];
        float*      hd = &hbuf[l & 1][0];
#pragma unroll
        for (int i = 0; i < NITER; ++i) {
            int k = t + i * NT;
            unsigned px = op[l][i].x;
            float A = *(const float*)(hs + (px & 0xffffu));
            float B = *(const float*)(hs + (px >> 16));
            COEFFS(op[l][i].y);
            hd[k] = fmaf(fmaf(CAB, B, CA), A, fmaf(CB, B, C1));
        }
        __syncthreads();
    }

    // ---- Layer 5 fused with GroupSum (reads hbuf[0], no write-back) ----
    float acc0 = 0.f, acc1 = 0.f;
    {
        const char* hs = (const char*)&hbuf[0][0];
#pragma unroll
        for (int i = 0; i < NITER; ++i) {
            unsigned px = op[5][i].x;
            float A = *(const float*)(hs + (px & 0xffffu));
            float B = *(const float*)(hs + (px >> 16));
            COEFFS(op[5][i].y);
            float o = fmaf(fmaf(CAB, B, CA), A, fmaf(CB, B, C1));
            if (i < NITER / 2) acc0 += o; else acc1 += o;   // class = (k >= 2048)
        }
    }
#pragma unroll
    for (int off = 32; off > 0; off >>= 1) {
        acc0 += __shfl_down(acc0, off);
        acc1 += __shfl_down(acc1, off);
    }
    int wave = t >> 6, lane = t & 63;
    if (lane == 0) { red[wave][0] = acc0; red[wave][1] = acc1; }
    __syncthreads();
    if (t == 0) {
        float s0 = 0.f, s1 = 0.f;
#pragma unroll
        for (int w = 0; w < NT / 64; ++w) { s0 += red[w][0]; s1 += red[w][1]; }
        red[0][0] = s0 * (1.0f / 255.0f);    // back to unit scale
        red[0][1] = s1 * (1.0f / 255.0f);
    }
    __syncthreads();
    const float2 tbl = make_float2(red[0][0], red[0][1]);

    // ---- Scatter: write tbl to every row whose pattern == p ----
#pragma unroll
    for (int i = 0; i < RPT; ++i) {
        int b = t + i * NT;
        int pat = (xr[i].x > 0.f ? 1 : 0) | (xr[i].y > 0.f ? 2 : 0);
        if (pat == p) out[b] = tbl;
    }
}

extern "C" void kernel_launch(void* const* d_in, const int* in_sizes, int n_in,
                              void* d_out, int out_size, void* d_ws, size_t ws_size,
                              hipStream_t stream) {
    const float* x    = (const float*)d_in[0];
    const float* w0   = (const float*)d_in[1];
    const float* ws   = (const float*)d_in[2];
    const int*   idx0 = (const int*)d_in[3];
    const int*   idxs = (const int*)d_in[4];
    float*       out  = (float*)d_out;
    uint2*       pk   = (uint2*)d_ws;    // LTOT*KN*8 B = 192 KB scratch

    pack_kernel<<<(LTOT * KN + 255) / 256, 256, 0, stream>>>(w0, ws, idx0, idxs, pk);
    netscatter_kernel<<<NPAT, NT, 0, stream>>>(x, pk, (float2*)out);
}